// Round 1
// 292.481 us; speedup vs baseline: 1.1280x; 1.1280x over previous
//
#include <hip/hip_runtime.h>

typedef unsigned short u16;
typedef unsigned int u32;
typedef float f32x4 __attribute__((ext_vector_type(4)));
typedef __bf16 bf16x8 __attribute__((ext_vector_type(8)));
typedef u32 u32x4 __attribute__((ext_vector_type(4)));
typedef u16 u16x4 __attribute__((ext_vector_type(4)));

#define NB 16
#define NSEQ 1024
#define NL 120
#define NLP 128
#define NC 1024
#define NH 16
#define NDH 64
#define KSP 72
#define VTP 136

__device__ __forceinline__ u16 f2bf(float f) {
  u32 u = __float_as_uint(f);
  return (u16)((u + 0x7fffu + ((u >> 16) & 1u)) >> 16);  // RNE
}

__device__ __forceinline__ void gld_lds16(const void* g, void* l) {
  __builtin_amdgcn_global_load_lds(
      (const __attribute__((address_space(1))) void*)g,
      (__attribute__((address_space(3))) void*)l, 16, 0, 0);
}

// phase-boundary fences: raw barrier (no implicit vmcnt(0) drain like
// __syncthreads) pinned by sched_barrier so ds_read/global_load_lds cannot
// migrate across phases (rule: compiler may hoist/sink across s_barrier).
#define SBAR()                               \
  do {                                       \
    __builtin_amdgcn_sched_barrier(0);       \
    __builtin_amdgcn_s_barrier();            \
    __builtin_amdgcn_sched_barrier(0);       \
  } while (0)
#define VMW(n)                                          \
  do {                                                  \
    __builtin_amdgcn_sched_barrier(0);                  \
    asm volatile("s_waitcnt vmcnt(" #n ")" ::: "memory"); \
  } while (0)

// one launch casts all five fp32 tensors to bf16; segment bounds compile-time
__global__ __launch_bounds__(256) void cast_all(
    const float* __restrict__ x, u16* __restrict__ xb,
    const float* __restrict__ cond, u16* __restrict__ condb,
    const float* __restrict__ Wq, u16* __restrict__ Wqb,
    const float* __restrict__ Wkv, u16* __restrict__ Wkvb,
    const float* __restrict__ Wp, u16* __restrict__ Wpb) {
  int bk = blockIdx.x;
  const float* src;
  u16* dst;
  if (bk < 16384) { src = x; dst = xb; }
  else if (bk < 18304) { src = cond; dst = condb; bk -= 16384; }
  else if (bk < 19328) { src = Wq; dst = Wqb; bk -= 18304; }
  else if (bk < 21376) { src = Wkv; dst = Wkvb; bk -= 19328; }
  else { src = Wp; dst = Wpb; bk -= 21376; }
  size_t i = ((size_t)bk * 256 + threadIdx.x) * 4;
  f32x4 v = *(const f32x4*)(src + i);
  u16x4 o;
  o.x = f2bf(v.x); o.y = f2bf(v.y); o.z = f2bf(v.z); o.w = f2bf(v.w);
  *(u16x4*)(dst + i) = o;
}

// ---------------------------------------------------------------------------
// 128x128 m97-structure GEMM: kept for the KV projection (M=1920 not /256).
// ---------------------------------------------------------------------------
template <bool OUT_F32>
__global__ __launch_bounds__(256) void gemm_bt(
    const u16* __restrict__ A, const u16* __restrict__ Bt,
    const float* __restrict__ bias, void* __restrict__ Cout,
    int M, int Nn, int K) {
  __shared__ u16 As[128 * 32];
  __shared__ u16 Bs[128 * 32];
  const int mt = M >> 7;
  const int bm = (int)blockIdx.x % mt;
  const int bn = (int)blockIdx.x / mt;
  const int m0 = bm << 7, n0 = bn << 7;
  const int tid = threadIdx.x;
  const int w = tid >> 6, lane = tid & 63;
  const int wm = (w & 1) << 6, wn = (w >> 1) << 6;
  const int quad = lane >> 4, l15 = lane & 15;

  f32x4 acc[4][4];
#pragma unroll
  for (int i = 0; i < 4; ++i)
#pragma unroll
    for (int j = 0; j < 4; ++j) acc[i][j] = (f32x4){0.f, 0.f, 0.f, 0.f};

  const int r0 = tid >> 2;
  const int cb = ((((tid & 3) - (r0 >> 1)) & 3)) << 3;
  const u16* aP = A + (size_t)(m0 + r0) * K + cb;
  const u16* bP = Bt + (size_t)(n0 + r0) * K + cb;
  u16* asDst = &As[r0 * 32 + ((tid & 3) << 3)];
  u16* bsDst = &Bs[r0 * 32 + ((tid & 3) << 3)];

  const int sw = ((quad + (l15 >> 1)) & 3) << 3;

  for (int k0 = 0; k0 < K; k0 += 32) {
    __syncthreads();
    gld_lds16(aP + k0, asDst);
    gld_lds16(aP + (size_t)64 * K + k0, asDst + 64 * 32);
    gld_lds16(bP + k0, bsDst);
    gld_lds16(bP + (size_t)64 * K + k0, bsDst + 64 * 32);
    __syncthreads();

    bf16x8 af[4], bfr[4];
#pragma unroll
    for (int i = 0; i < 4; ++i)
      af[i] = *(const bf16x8*)&As[(wm + i * 16 + l15) * 32 + sw];
#pragma unroll
    for (int j = 0; j < 4; ++j)
      bfr[j] = *(const bf16x8*)&Bs[(wn + j * 16 + l15) * 32 + sw];
#pragma unroll
    for (int i = 0; i < 4; ++i)
#pragma unroll
      for (int j = 0; j < 4; ++j)
        acc[i][j] =
            __builtin_amdgcn_mfma_f32_16x16x32_bf16(af[i], bfr[j], acc[i][j], 0, 0, 0);
  }

#pragma unroll
  for (int j = 0; j < 4; ++j) {
    const int col = n0 + wn + j * 16 + l15;
    const float bv = bias[col];
#pragma unroll
    for (int i = 0; i < 4; ++i) {
      const int row = m0 + wm + i * 16 + quad * 4;
#pragma unroll
      for (int r = 0; r < 4; ++r) {
        const float v = acc[i][j][r] + bv;
        if (OUT_F32)
          ((float*)Cout)[(size_t)(row + r) * Nn + col] = v;
        else
          ((u16*)Cout)[(size_t)(row + r) * Nn + col] = f2bf(v);
      }
    }
  }
}

// ---------------------------------------------------------------------------
// 256x256-tile, BK=64, 8-wave, 8-phase pipelined GEMM (HK-style schedule).
// C = A(MxK) * Bt(NxK)^T + bias.  Requires M%256==0, N%256==0, K%128==0.
//
// LDS: S[A/B][buf][half][128x64 bf16] = 128 KiB. Half-tile = 128 rows x 64 k.
// Each half is stored with a 16B-slot XOR swizzle: stored(row, cb) holds
// logical col cb ^ ((row&7)<<4). global_load_lds writes linearly (dst =
// wave-uniform + lane*16) so the swizzle is applied by permuting the per-lane
// GLOBAL source column (same 128B row-segment -> coalescing intact), and the
// same XOR on the ds_read side (rule: both-sides-or-neither).
//
// Per iteration (2 K-tiles, 8 phases): phase = {ds_read frags | stage 1
// half-tile | barrier | MFMA x16 (setprio) | [vmcnt(6) even phases] barrier}.
// Wave (wr=w&1, wc=w>>1) owns rows {wr*64, 128+wr*64} x cols {wc*32, 128+wc*32}
// (split across halves so each phase touches only 1-2 LDS regions).
// Quadrant order (lo,lo),(lo,hi),(hi,hi),(hi,lo); B-frags of both halves are
// kept in registers so phase 4/8 issue no ds_reads.
//
// Stage schedule (iteration it, T0=2it buf0 ph1-4, T1=2it+1 buf1 ph5-8):
//   ph1:T1.Blo ph2:T1.Ahi ph3:T2.Alo ph4:T2.Bhi
//   ph5:T2.Blo ph6:T2.Ahi ph7:T3.Alo ph8:T3.Bhi
// Checked on paper: every half staged >=4 phases before first read (covered
// by vmcnt(6) at phases 2/4/6/8 = 3 half-tiles in flight, never drained to 0)
// and >=1 barrier after its region's last ds_read (WAR-safe).
// ---------------------------------------------------------------------------
template <bool OUT_F32>
__global__ __launch_bounds__(512, 2) void gemm256(
    const u16* __restrict__ A, const u16* __restrict__ Bt,
    const float* __restrict__ bias, void* __restrict__ Cout,
    int M, int Nn, int K) {
  __shared__ u16 S[2][2][2][8192];  // [A/B][buf][half][128*64]

  const int bid = (int)blockIdx.x;
  const int nwg = (M >> 8) * (Nn >> 8);
  // XCD swizzle (nwg%8==0 for our shapes): contiguous chunk per XCD.
  const int cpx = nwg >> 3;
  const int swz = (bid & 7) * cpx + (bid >> 3);
  const int mt = M >> 8;
  const int bm = swz % mt, bn = swz / mt;
  const int m0 = bm << 8, n0 = bn << 8;

  const int tid = threadIdx.x;
  const int w = tid >> 6, lane = tid & 63;
  const int quad = lane >> 4, l15 = lane & 15;
  const int wr = w & 1, wc = w >> 1;

  // staging: thread covers stored row srow (j=0) and srow+64 (j=1),
  // stored 16B slot (tid&7); logical k-slot = slot ^ (srow&7).
  const int srow = tid >> 3;
  const int xoff = (((tid & 7) ^ (srow & 7)) << 3);  // u16 units
  const u16* aB0 = A + (size_t)(m0 + srow) * K + xoff;
  const u16* bB0 = Bt + (size_t)(n0 + srow) * K + xoff;
  const size_t rowK64 = (size_t)64 * K;
  const size_t rowK128 = (size_t)128 * K;

  auto STAGE = [&](int ab, int buf, int half, int t) {
    const u16* g = (ab ? bB0 : aB0) + half * rowK128 + t * 64;
    u16* d = &S[ab][buf][half][0] + tid * 8;
    gld_lds16(g, d);
    gld_lds16(g + rowK64, d + 4096);
  };

  // frag-read byte offsets (swizzled): row&7 == l15&7 for all frag rows.
  const int c0 = ((quad << 4) ^ ((l15 & 7) << 4));
  const int c1 = c0 ^ 64;
  const int arow = (wr * 64 + l15) * 128;  // bytes within A half
  const int brow = (wc * 32 + l15) * 128;  // bytes within B half

  bf16x8 af[4][2], bfl[2][2], bfh[2][2];
  auto LDA = [&](int buf, int rh) {
    const char* base = (const char*)&S[0][buf][rh][0] + arow;
#pragma unroll
    for (int f = 0; f < 4; ++f) {
      af[f][0] = *(const bf16x8*)(base + f * 2048 + c0);
      af[f][1] = *(const bf16x8*)(base + f * 2048 + c1);
    }
  };
  auto LDB = [&](bf16x8(&bf)[2][2], int buf, int ch) {
    const char* base = (const char*)&S[1][buf][ch][0] + brow;
#pragma unroll
    for (int g = 0; g < 2; ++g) {
      bf[g][0] = *(const bf16x8*)(base + g * 2048 + c0);
      bf[g][1] = *(const bf16x8*)(base + g * 2048 + c1);
    }
  };

  f32x4 a_ll[4][2], a_lh[4][2], a_hh[4][2], a_hl[4][2];
#pragma unroll
  for (int f = 0; f < 4; ++f)
#pragma unroll
    for (int g = 0; g < 2; ++g) {
      a_ll[f][g] = (f32x4){0.f, 0.f, 0.f, 0.f};
      a_lh[f][g] = (f32x4){0.f, 0.f, 0.f, 0.f};
      a_hh[f][g] = (f32x4){0.f, 0.f, 0.f, 0.f};
      a_hl[f][g] = (f32x4){0.f, 0.f, 0.f, 0.f};
    }

  auto MM = [&](f32x4(&acc)[4][2], bf16x8(&bf)[2][2]) {
    __builtin_amdgcn_s_setprio(1);
#pragma unroll
    for (int f = 0; f < 4; ++f)
#pragma unroll
      for (int g = 0; g < 2; ++g) {
        acc[f][g] = __builtin_amdgcn_mfma_f32_16x16x32_bf16(af[f][0], bf[g][0],
                                                            acc[f][g], 0, 0, 0);
        acc[f][g] = __builtin_amdgcn_mfma_f32_16x16x32_bf16(af[f][1], bf[g][1],
                                                            acc[f][g], 0, 0, 0);
      }
    __builtin_amdgcn_s_setprio(0);
  };

  const int NT = K >> 6;   // 64-wide K-tiles
  const int NIT = K >> 7;  // iterations (2 tiles each)

  // prologue: T0 fully + T1.{Alo,Bhi}; leave T1's 2 halves (4 loads) in flight.
  STAGE(0, 0, 0, 0); STAGE(0, 0, 1, 0); STAGE(1, 0, 0, 0); STAGE(1, 0, 1, 0);
  STAGE(0, 1, 0, 1); STAGE(1, 1, 1, 1);
  VMW(4);
  SBAR();

#pragma unroll 1
  for (int it = 0; it < NIT; ++it) {
    const int t1 = 2 * it + 1;
    int t2 = 2 * it + 2; if (t2 > NT - 1) t2 = NT - 1;
    int t3 = 2 * it + 3; if (t3 > NT - 1) t3 = NT - 1;
    // ph1: Q(lo,lo) on buf0
    LDA(0, 0); LDB(bfl, 0, 0); STAGE(1, 1, 0, t1);
    SBAR(); MM(a_ll, bfl); SBAR();
    // ph2: Q(lo,hi)
    LDB(bfh, 0, 1); STAGE(0, 1, 1, t1);
    SBAR(); MM(a_lh, bfh); VMW(6); SBAR();
    // ph3: Q(hi,hi)
    LDA(0, 1); STAGE(0, 0, 0, t2);
    SBAR(); MM(a_hh, bfh); SBAR();
    // ph4: Q(hi,lo) — no ds_reads (af_hi + bfl live)
    STAGE(1, 0, 1, t2);
    SBAR(); MM(a_hl, bfl); VMW(6); SBAR();
    // ph5: Q(lo,lo) on buf1
    LDA(1, 0); LDB(bfl, 1, 0); STAGE(1, 0, 0, t2);
    SBAR(); MM(a_ll, bfl); SBAR();
    // ph6
    LDB(bfh, 1, 1); STAGE(0, 0, 1, t2);
    SBAR(); MM(a_lh, bfh); VMW(6); SBAR();
    // ph7
    LDA(1, 1); STAGE(0, 1, 0, t3);
    SBAR(); MM(a_hh, bfh); SBAR();
    // ph8
    STAGE(1, 1, 1, t3);
    SBAR(); MM(a_hl, bfl); VMW(6); SBAR();
  }

  // epilogue: C/D layout col=lane&15, row=quad*4+reg  [verified m89/m91]
  auto EPI = [&](f32x4(&acc)[4][2], int rh, int ch) {
#pragma unroll
    for (int g = 0; g < 2; ++g) {
      const int col = n0 + ch * 128 + wc * 32 + g * 16 + l15;
      const float bv = bias[col];
#pragma unroll
      for (int f = 0; f < 4; ++f) {
        const int row = m0 + rh * 128 + wr * 64 + f * 16 + quad * 4;
#pragma unroll
        for (int r = 0; r < 4; ++r) {
          const float v = acc[f][g][r] + bv;
          if (OUT_F32)
            ((float*)Cout)[(size_t)(row + r) * Nn + col] = v;
          else
            ((u16*)Cout)[(size_t)(row + r) * Nn + col] = f2bf(v);
        }
      }
    }
  };
  EPI(a_ll, 0, 0); EPI(a_lh, 0, 1); EPI(a_hh, 1, 1); EPI(a_hl, 1, 0);
}

// one block per (b,h,chunk-of-256-queries); K/V/mask staged in LDS once;
// 4 waves x 16 queries/iter x 4 iters.
__global__ __launch_bounds__(256) void attn(
    const u16* __restrict__ Qb, const u16* __restrict__ KVb,
    const int* __restrict__ mask, u16* __restrict__ Ob) {
  __shared__ u16 Ks[NLP * KSP];
  __shared__ u16 Vt[NDH * VTP];
  __shared__ float mb[NLP];
  __shared__ u16 pb[4][16 * VTP];

  const int chunk = (int)blockIdx.x & 3;
  const int h = ((int)blockIdx.x >> 2) & 15;
  const int b = (int)blockIdx.x >> 6;
  const int tid = threadIdx.x;
  const int w = tid >> 6, lane = tid & 63;
  const int quad = lane >> 4, l15 = lane & 15;
  const u16* kvbase = KVb + (size_t)b * NL * 2 * NC;

  for (int i = tid; i < NLP * 8; i += 256) {
    const int l = i >> 3, c8 = (i & 7) * 8;
    u32x4 z = {0u, 0u, 0u, 0u};
    u32x4 v = (l < NL) ? *(const u32x4*)(kvbase + (size_t)l * 2 * NC + h * NDH + c8) : z;
    *(u32x4*)&Ks[l * KSP + c8] = v;
  }
  u16* vstage = &pb[0][0];
  for (int i = tid; i < NL * 8; i += 256) {
    const int l = i >> 3, c8 = (i & 7) * 8;
    *(u32x4*)&vstage[l * NDH + c8] =
        *(const u32x4*)(kvbase + (size_t)l * 2 * NC + NC + h * NDH + c8);
  }
  for (int i = tid; i < NLP; i += 256)
    mb[i] = (i < NL && mask[b * NL + i] != 0) ? 0.0f : -1e30f;
  __syncthreads();
  for (int i = tid; i < NDH * NLP; i += 256) {
    const int d = i >> 7, l = i & 127;
    Vt[d * VTP + l] = (l < NL) ? vstage[l * NDH + d] : (u16)0;
  }
  __syncthreads();

  const float scale = 0.125f;
  for (int it = 0; it < 4; ++it) {
    const int q0 = chunk * 256 + it * 64 + w * 16;
    const u16* qptr = Qb + (size_t)(b * NSEQ + q0 + l15) * NC + h * NDH + quad * 8;
    const bf16x8 a0 = *(const bf16x8*)qptr;
    const bf16x8 a1 = *(const bf16x8*)(qptr + 32);

    f32x4 s[8];
#pragma unroll
    for (int kt = 0; kt < 8; ++kt) {
      const u16* kb = &Ks[(kt * 16 + l15) * KSP + quad * 8];
      const bf16x8 b0 = *(const bf16x8*)kb;
      const bf16x8 b1 = *(const bf16x8*)(kb + 32);
      f32x4 t = {0.f, 0.f, 0.f, 0.f};
      t = __builtin_amdgcn_mfma_f32_16x16x32_bf16(a0, b0, t, 0, 0, 0);
      t = __builtin_amdgcn_mfma_f32_16x16x32_bf16(a1, b1, t, 0, 0, 0);
      s[kt] = t;
    }
#pragma unroll
    for (int kt = 0; kt < 8; ++kt) {
      const float mbv = mb[kt * 16 + l15];
#pragma unroll
      for (int r = 0; r < 4; ++r) s[kt][r] = s[kt][r] * scale + mbv;
    }
    float sum[4];
#pragma unroll
    for (int r = 0; r < 4; ++r) {
      float m = s[0][r];
#pragma unroll
      for (int kt = 1; kt < 8; ++kt) m = fmaxf(m, s[kt][r]);
      m = fmaxf(m, __shfl_xor(m, 1));
      m = fmaxf(m, __shfl_xor(m, 2));
      m = fmaxf(m, __shfl_xor(m, 4));
      m = fmaxf(m, __shfl_xor(m, 8));
      float su = 0.f;
#pragma unroll
      for (int kt = 0; kt < 8; ++kt) {
        s[kt][r] = __expf(s[kt][r] - m);
        su += s[kt][r];
      }
      su += __shfl_xor(su, 1);
      su += __shfl_xor(su, 2);
      su += __shfl_xor(su, 4);
      su += __shfl_xor(su, 8);
      sum[r] = su;
    }
#pragma unroll
    for (int r = 0; r < 4; ++r) {
      const float inv = 1.0f / sum[r];
#pragma unroll
      for (int kt = 0; kt < 8; ++kt)
        pb[w][(quad * 4 + r) * VTP + kt * 16 + l15] = f2bf(s[kt][r] * inv);
    }
#pragma unroll
    for (int ntl = 0; ntl < 4; ++ntl) {
      f32x4 o = {0.f, 0.f, 0.f, 0.f};
#pragma unroll
      for (int kt = 0; kt < 4; ++kt) {
        const bf16x8 pa = *(const bf16x8*)&pb[w][l15 * VTP + kt * 32 + quad * 8];
        const bf16x8 vb = *(const bf16x8*)&Vt[(ntl * 16 + l15) * VTP + kt * 32 + quad * 8];
        o = __builtin_amdgcn_mfma_f32_16x16x32_bf16(pa, vb, o, 0, 0, 0);
      }
#pragma unroll
      for (int r = 0; r < 4; ++r)
        Ob[(size_t)(b * NSEQ + q0 + quad * 4 + r) * NC + h * NDH + ntl * 16 + l15] =
            f2bf(o[r]);
    }
  }
}

extern "C" void kernel_launch(void* const* d_in, const int* in_sizes, int n_in,
                              void* d_out, int out_size, void* d_ws, size_t ws_size,
                              hipStream_t stream) {
  const float* x = (const float*)d_in[0];
  const float* cond = (const float*)d_in[1];
  const int* mask = (const int*)d_in[2];
  const float* Wq = (const float*)d_in[3];
  const float* bq = (const float*)d_in[4];
  const float* Wkv = (const float*)d_in[5];
  const float* bkv = (const float*)d_in[6];
  const float* Wp = (const float*)d_in[7];
  const float* bp = (const float*)d_in[8];

  char* ws = (char*)d_ws;
  u16* xb = (u16*)(ws + 0);
  u16* condb = (u16*)(ws + 33554432);
  u16* Wqb = (u16*)(ws + 37486592);
  u16* Wkvb = (u16*)(ws + 39583744);
  u16* Wpb = (u16*)(ws + 43778048);
  u16* Qb = (u16*)(ws + 45875200);
  u16* KVb = (u16*)(ws + 79429632);
  u16* Ob = xb;

  cast_all<<<22400, 256, 0, stream>>>(x, xb, cond, condb, Wq, Wqb, Wkv, Wkvb, Wp, Wpb);

  gemm256<false><<<256, 512, 0, stream>>>(xb, Wqb, bq, Qb, 16384, 1024, 1024);
  gemm_bt<false><<<15 * 16, 256, 0, stream>>>(condb, Wkvb, bkv, KVb, 1920, 2048, 1024);
  attn<<<1024, 256, 0, stream>>>(Qb, KVb, mask, Ob);
  gemm256<true><<<256, 512, 0, stream>>>(Ob, Wpb, bp, d_out, 16384, 1024, 1024);
}

// Round 2
// 278.648 us; speedup vs baseline: 1.1840x; 1.0496x over previous
//
#include <hip/hip_runtime.h>

typedef unsigned short u16;
typedef unsigned int u32;
typedef float f32x4 __attribute__((ext_vector_type(4)));
typedef __bf16 bf16x8 __attribute__((ext_vector_type(8)));
typedef u32 u32x4 __attribute__((ext_vector_type(4)));
typedef u16 u16x4 __attribute__((ext_vector_type(4)));

#define NB 16
#define NSEQ 1024
#define NL 120
#define NLP 128
#define NC 1024
#define NH 16
#define NDH 64
#define KSP 72
#define VTP 136

__device__ __forceinline__ u16 f2bf(float f) {
  u32 u = __float_as_uint(f);
  return (u16)((u + 0x7fffu + ((u >> 16) & 1u)) >> 16);  // RNE
}

__device__ __forceinline__ void gld_lds16(const void* g, void* l) {
  __builtin_amdgcn_global_load_lds(
      (const __attribute__((address_space(1))) void*)g,
      (__attribute__((address_space(3))) void*)l, 16, 0, 0);
}

#define SBAR()                               \
  do {                                       \
    __builtin_amdgcn_sched_barrier(0);       \
    __builtin_amdgcn_s_barrier();            \
    __builtin_amdgcn_sched_barrier(0);       \
  } while (0)
#define VMW(n)                                          \
  do {                                                  \
    __builtin_amdgcn_sched_barrier(0);                  \
    asm volatile("s_waitcnt vmcnt(" #n ")" ::: "memory"); \
  } while (0)

// one launch casts all five fp32 tensors to bf16; segment bounds compile-time
__global__ __launch_bounds__(256) void cast_all(
    const float* __restrict__ x, u16* __restrict__ xb,
    const float* __restrict__ cond, u16* __restrict__ condb,
    const float* __restrict__ Wq, u16* __restrict__ Wqb,
    const float* __restrict__ Wkv, u16* __restrict__ Wkvb,
    const float* __restrict__ Wp, u16* __restrict__ Wpb) {
  int bk = blockIdx.x;
  const float* src;
  u16* dst;
  if (bk < 16384) { src = x; dst = xb; }
  else if (bk < 18304) { src = cond; dst = condb; bk -= 16384; }
  else if (bk < 19328) { src = Wq; dst = Wqb; bk -= 18304; }
  else if (bk < 21376) { src = Wkv; dst = Wkvb; bk -= 19328; }
  else { src = Wp; dst = Wpb; bk -= 21376; }
  size_t i = ((size_t)bk * 256 + threadIdx.x) * 4;
  f32x4 v = *(const f32x4*)(src + i);
  u16x4 o;
  o.x = f2bf(v.x); o.y = f2bf(v.y); o.z = f2bf(v.z); o.w = f2bf(v.w);
  *(u16x4*)(dst + i) = o;
}

// ---------------------------------------------------------------------------
// 128x128 m97-structure GEMM: kept for the KV projection (M=1920 not /256).
// ---------------------------------------------------------------------------
template <bool OUT_F32>
__global__ __launch_bounds__(256) void gemm_bt(
    const u16* __restrict__ A, const u16* __restrict__ Bt,
    const float* __restrict__ bias, void* __restrict__ Cout,
    int M, int Nn, int K) {
  __shared__ u16 As[128 * 32];
  __shared__ u16 Bs[128 * 32];
  const int mt = M >> 7;
  const int bm = (int)blockIdx.x % mt;
  const int bn = (int)blockIdx.x / mt;
  const int m0 = bm << 7, n0 = bn << 7;
  const int tid = threadIdx.x;
  const int w = tid >> 6, lane = tid & 63;
  const int wm = (w & 1) << 6, wn = (w >> 1) << 6;
  const int quad = lane >> 4, l15 = lane & 15;

  f32x4 acc[4][4];
#pragma unroll
  for (int i = 0; i < 4; ++i)
#pragma unroll
    for (int j = 0; j < 4; ++j) acc[i][j] = (f32x4){0.f, 0.f, 0.f, 0.f};

  const int r0 = tid >> 2;
  const int cb = ((((tid & 3) - (r0 >> 1)) & 3)) << 3;
  const u16* aP = A + (size_t)(m0 + r0) * K + cb;
  const u16* bP = Bt + (size_t)(n0 + r0) * K + cb;
  u16* asDst = &As[r0 * 32 + ((tid & 3) << 3)];
  u16* bsDst = &Bs[r0 * 32 + ((tid & 3) << 3)];

  const int sw = ((quad + (l15 >> 1)) & 3) << 3;

  for (int k0 = 0; k0 < K; k0 += 32) {
    __syncthreads();
    gld_lds16(aP + k0, asDst);
    gld_lds16(aP + (size_t)64 * K + k0, asDst + 64 * 32);
    gld_lds16(bP + k0, bsDst);
    gld_lds16(bP + (size_t)64 * K + k0, bsDst + 64 * 32);
    __syncthreads();

    bf16x8 af[4], bfr[4];
#pragma unroll
    for (int i = 0; i < 4; ++i)
      af[i] = *(const bf16x8*)&As[(wm + i * 16 + l15) * 32 + sw];
#pragma unroll
    for (int j = 0; j < 4; ++j)
      bfr[j] = *(const bf16x8*)&Bs[(wn + j * 16 + l15) * 32 + sw];
#pragma unroll
    for (int i = 0; i < 4; ++i)
#pragma unroll
      for (int j = 0; j < 4; ++j)
        acc[i][j] =
            __builtin_amdgcn_mfma_f32_16x16x32_bf16(af[i], bfr[j], acc[i][j], 0, 0, 0);
  }

#pragma unroll
  for (int j = 0; j < 4; ++j) {
    const int col = n0 + wn + j * 16 + l15;
    const float bv = bias[col];
#pragma unroll
    for (int i = 0; i < 4; ++i) {
      const int row = m0 + wm + i * 16 + quad * 4;
#pragma unroll
      for (int r = 0; r < 4; ++r) {
        const float v = acc[i][j][r] + bv;
        if (OUT_F32)
          ((float*)Cout)[(size_t)(row + r) * Nn + col] = v;
        else
          ((u16*)Cout)[(size_t)(row + r) * Nn + col] = f2bf(v);
      }
    }
  }
}

// ---------------------------------------------------------------------------
// 256x256-tile, BK=64, 8-wave, 8-phase pipelined GEMM (HK-style schedule).
// (unchanged from R1 — see R1 comments; attn is this round's target)
// ---------------------------------------------------------------------------
template <bool OUT_F32>
__global__ __launch_bounds__(512, 2) void gemm256(
    const u16* __restrict__ A, const u16* __restrict__ Bt,
    const float* __restrict__ bias, void* __restrict__ Cout,
    int M, int Nn, int K) {
  __shared__ u16 S[2][2][2][8192];  // [A/B][buf][half][128*64]

  const int bid = (int)blockIdx.x;
  const int nwg = (M >> 8) * (Nn >> 8);
  const int cpx = nwg >> 3;
  const int swz = (bid & 7) * cpx + (bid >> 3);
  const int mt = M >> 8;
  const int bm = swz % mt, bn = swz / mt;
  const int m0 = bm << 8, n0 = bn << 8;

  const int tid = threadIdx.x;
  const int w = tid >> 6, lane = tid & 63;
  const int quad = lane >> 4, l15 = lane & 15;
  const int wr = w & 1, wc = w >> 1;

  const int srow = tid >> 3;
  const int xoff = (((tid & 7) ^ (srow & 7)) << 3);  // u16 units
  const u16* aB0 = A + (size_t)(m0 + srow) * K + xoff;
  const u16* bB0 = Bt + (size_t)(n0 + srow) * K + xoff;
  const size_t rowK64 = (size_t)64 * K;
  const size_t rowK128 = (size_t)128 * K;

  auto STAGE = [&](int ab, int buf, int half, int t) {
    const u16* g = (ab ? bB0 : aB0) + half * rowK128 + t * 64;
    u16* d = &S[ab][buf][half][0] + tid * 8;
    gld_lds16(g, d);
    gld_lds16(g + rowK64, d + 4096);
  };

  const int c0 = ((quad << 4) ^ ((l15 & 7) << 4));
  const int c1 = c0 ^ 64;
  const int arow = (wr * 64 + l15) * 128;  // bytes within A half
  const int brow = (wc * 32 + l15) * 128;  // bytes within B half

  bf16x8 af[4][2], bfl[2][2], bfh[2][2];
  auto LDA = [&](int buf, int rh) {
    const char* base = (const char*)&S[0][buf][rh][0] + arow;
#pragma unroll
    for (int f = 0; f < 4; ++f) {
      af[f][0] = *(const bf16x8*)(base + f * 2048 + c0);
      af[f][1] = *(const bf16x8*)(base + f * 2048 + c1);
    }
  };
  auto LDB = [&](bf16x8(&bf)[2][2], int buf, int ch) {
    const char* base = (const char*)&S[1][buf][ch][0] + brow;
#pragma unroll
    for (int g = 0; g < 2; ++g) {
      bf[g][0] = *(const bf16x8*)(base + g * 2048 + c0);
      bf[g][1] = *(const bf16x8*)(base + g * 2048 + c1);
    }
  };

  f32x4 a_ll[4][2], a_lh[4][2], a_hh[4][2], a_hl[4][2];
#pragma unroll
  for (int f = 0; f < 4; ++f)
#pragma unroll
    for (int g = 0; g < 2; ++g) {
      a_ll[f][g] = (f32x4){0.f, 0.f, 0.f, 0.f};
      a_lh[f][g] = (f32x4){0.f, 0.f, 0.f, 0.f};
      a_hh[f][g] = (f32x4){0.f, 0.f, 0.f, 0.f};
      a_hl[f][g] = (f32x4){0.f, 0.f, 0.f, 0.f};
    }

  auto MM = [&](f32x4(&acc)[4][2], bf16x8(&bf)[2][2]) {
    __builtin_amdgcn_s_setprio(1);
#pragma unroll
    for (int f = 0; f < 4; ++f)
#pragma unroll
      for (int g = 0; g < 2; ++g) {
        acc[f][g] = __builtin_amdgcn_mfma_f32_16x16x32_bf16(af[f][0], bf[g][0],
                                                            acc[f][g], 0, 0, 0);
        acc[f][g] = __builtin_amdgcn_mfma_f32_16x16x32_bf16(af[f][1], bf[g][1],
                                                            acc[f][g], 0, 0, 0);
      }
    __builtin_amdgcn_s_setprio(0);
  };

  const int NT = K >> 6;
  const int NIT = K >> 7;

  STAGE(0, 0, 0, 0); STAGE(0, 0, 1, 0); STAGE(1, 0, 0, 0); STAGE(1, 0, 1, 0);
  STAGE(0, 1, 0, 1); STAGE(1, 1, 1, 1);
  VMW(4);
  SBAR();

#pragma unroll 1
  for (int it = 0; it < NIT; ++it) {
    const int t1 = 2 * it + 1;
    int t2 = 2 * it + 2; if (t2 > NT - 1) t2 = NT - 1;
    int t3 = 2 * it + 3; if (t3 > NT - 1) t3 = NT - 1;
    LDA(0, 0); LDB(bfl, 0, 0); STAGE(1, 1, 0, t1);
    SBAR(); MM(a_ll, bfl); SBAR();
    LDB(bfh, 0, 1); STAGE(0, 1, 1, t1);
    SBAR(); MM(a_lh, bfh); VMW(6); SBAR();
    LDA(0, 1); STAGE(0, 0, 0, t2);
    SBAR(); MM(a_hh, bfh); SBAR();
    STAGE(1, 0, 1, t2);
    SBAR(); MM(a_hl, bfl); VMW(6); SBAR();
    LDA(1, 0); LDB(bfl, 1, 0); STAGE(1, 0, 0, t2);
    SBAR(); MM(a_ll, bfl); SBAR();
    LDB(bfh, 1, 1); STAGE(0, 0, 1, t2);
    SBAR(); MM(a_lh, bfh); VMW(6); SBAR();
    LDA(1, 1); STAGE(0, 1, 0, t3);
    SBAR(); MM(a_hh, bfh); SBAR();
    STAGE(1, 1, 1, t3);
    SBAR(); MM(a_hl, bfl); VMW(6); SBAR();
  }

  auto EPI = [&](f32x4(&acc)[4][2], int rh, int ch) {
#pragma unroll
    for (int g = 0; g < 2; ++g) {
      const int col = n0 + ch * 128 + wc * 32 + g * 16 + l15;
      const float bv = bias[col];
#pragma unroll
      for (int f = 0; f < 4; ++f) {
        const int row = m0 + rh * 128 + wr * 64 + f * 16 + quad * 4;
#pragma unroll
        for (int r = 0; r < 4; ++r) {
          const float v = acc[f][g][r] + bv;
          if (OUT_F32)
            ((float*)Cout)[(size_t)(row + r) * Nn + col] = v;
          else
            ((u16*)Cout)[(size_t)(row + r) * Nn + col] = f2bf(v);
        }
      }
    }
  };
  EPI(a_ll, 0, 0); EPI(a_lh, 0, 1); EPI(a_hh, 1, 1); EPI(a_hl, 1, 0);
}

// one block per (b,h,chunk-of-256-queries); K/V/mask staged in LDS once;
// 4 waves x 16 queries/iter x 4 iters.
// R2: (a) V-transpose remapped — old version read a column of row-major
// [128][64] with 64 lanes at 128B stride = all-bank-0, ~32-way conflict;
// that one loop was the ENTIRE 8.39M SQ_LDS_BANK_CONFLICT (8192 cyc/block
// x 1024 blocks = 2^23). New mapping: lane d=tid&63 reads 4 rows' column d
// (scalar reads at byte l*128+2d -> consecutive dwords, conflict-free) and
// writes one 8B u16x4 to Vt[d][4*l4] (8 distinct banks, bounded ~2x floor).
// (b) Q fragments for iteration it+1 prefetched before QK^T(it) so the
// ~600-900cy global latency hides under softmax+PV instead of being exposed
// at each iteration head.
__global__ __launch_bounds__(256) void attn(
    const u16* __restrict__ Qb, const u16* __restrict__ KVb,
    const int* __restrict__ mask, u16* __restrict__ Ob) {
  __shared__ u16 Ks[NLP * KSP];
  __shared__ u16 Vt[NDH * VTP];
  __shared__ float mb[NLP];
  __shared__ u16 pb[4][16 * VTP];

  const int chunk = (int)blockIdx.x & 3;
  const int h = ((int)blockIdx.x >> 2) & 15;
  const int b = (int)blockIdx.x >> 6;
  const int tid = threadIdx.x;
  const int w = tid >> 6, lane = tid & 63;
  const int quad = lane >> 4, l15 = lane & 15;
  const u16* kvbase = KVb + (size_t)b * NL * 2 * NC;

  for (int i = tid; i < NLP * 8; i += 256) {
    const int l = i >> 3, c8 = (i & 7) * 8;
    u32x4 z = {0u, 0u, 0u, 0u};
    u32x4 v = (l < NL) ? *(const u32x4*)(kvbase + (size_t)l * 2 * NC + h * NDH + c8) : z;
    *(u32x4*)&Ks[l * KSP + c8] = v;
  }
  u16* vstage = &pb[0][0];
  for (int i = tid; i < NL * 8; i += 256) {
    const int l = i >> 3, c8 = (i & 7) * 8;
    *(u32x4*)&vstage[l * NDH + c8] =
        *(const u32x4*)(kvbase + (size_t)l * 2 * NC + NC + h * NDH + c8);
  }
  for (int i = tid; i < NLP; i += 256)
    mb[i] = (i < NL && mask[b * NL + i] != 0) ? 0.0f : -1e30f;
  __syncthreads();
  // conflict-free transpose: d = tid&63 (one dh column per lane),
  // 4-row groups l4; reads consecutive-dword, write one 8B chunk.
  {
    const int d = tid & 63;
#pragma unroll
    for (int it2 = 0; it2 < 8; ++it2) {
      const int l4 = (tid >> 6) + it2 * 4;  // 0..31
      u16x4 vv;
      if (l4 < 30) {  // rows l4*4 .. l4*4+3 < NL=120
        vv.x = vstage[(l4 * 4 + 0) * NDH + d];
        vv.y = vstage[(l4 * 4 + 1) * NDH + d];
        vv.z = vstage[(l4 * 4 + 2) * NDH + d];
        vv.w = vstage[(l4 * 4 + 3) * NDH + d];
      } else {
        vv = (u16x4){0, 0, 0, 0};
      }
      *(u16x4*)&Vt[d * VTP + l4 * 4] = vv;
    }
  }
  __syncthreads();

  const float scale = 0.125f;
  // Q prefetch (rotating registers; no runtime-indexed arrays)
  const u16* qbase = Qb + (size_t)(b * NSEQ + chunk * 256 + l15) * NC + h * NDH + quad * 8;
  bf16x8 a0 = *(const bf16x8*)(qbase + (size_t)(0 * 64 + w * 16) * NC);
  bf16x8 a1 = *(const bf16x8*)(qbase + (size_t)(0 * 64 + w * 16) * NC + 32);

  for (int it = 0; it < 4; ++it) {
    const int q0 = chunk * 256 + it * 64 + w * 16;
    // prefetch next iteration's Q before using this one
    const int itn = (it + 1) & 3;
    const u16* qn = qbase + (size_t)(itn * 64 + w * 16) * NC;
    const bf16x8 n0 = *(const bf16x8*)qn;
    const bf16x8 n1 = *(const bf16x8*)(qn + 32);

    f32x4 s[8];
#pragma unroll
    for (int kt = 0; kt < 8; ++kt) {
      const u16* kb = &Ks[(kt * 16 + l15) * KSP + quad * 8];
      const bf16x8 b0 = *(const bf16x8*)kb;
      const bf16x8 b1 = *(const bf16x8*)(kb + 32);
      f32x4 t = {0.f, 0.f, 0.f, 0.f};
      t = __builtin_amdgcn_mfma_f32_16x16x32_bf16(a0, b0, t, 0, 0, 0);
      t = __builtin_amdgcn_mfma_f32_16x16x32_bf16(a1, b1, t, 0, 0, 0);
      s[kt] = t;
    }
#pragma unroll
    for (int kt = 0; kt < 8; ++kt) {
      const float mbv = mb[kt * 16 + l15];
#pragma unroll
      for (int r = 0; r < 4; ++r) s[kt][r] = s[kt][r] * scale + mbv;
    }
    float sum[4];
#pragma unroll
    for (int r = 0; r < 4; ++r) {
      float m = s[0][r];
#pragma unroll
      for (int kt = 1; kt < 8; ++kt) m = fmaxf(m, s[kt][r]);
      m = fmaxf(m, __shfl_xor(m, 1));
      m = fmaxf(m, __shfl_xor(m, 2));
      m = fmaxf(m, __shfl_xor(m, 4));
      m = fmaxf(m, __shfl_xor(m, 8));
      float su = 0.f;
#pragma unroll
      for (int kt = 0; kt < 8; ++kt) {
        s[kt][r] = __expf(s[kt][r] - m);
        su += s[kt][r];
      }
      su += __shfl_xor(su, 1);
      su += __shfl_xor(su, 2);
      su += __shfl_xor(su, 4);
      su += __shfl_xor(su, 8);
      sum[r] = su;
    }
#pragma unroll
    for (int r = 0; r < 4; ++r) {
      const float inv = 1.0f / sum[r];
#pragma unroll
      for (int kt = 0; kt < 8; ++kt)
        pb[w][(quad * 4 + r) * VTP + kt * 16 + l15] = f2bf(s[kt][r] * inv);
    }
#pragma unroll
    for (int ntl = 0; ntl < 4; ++ntl) {
      f32x4 o = {0.f, 0.f, 0.f, 0.f};
#pragma unroll
      for (int kt = 0; kt < 4; ++kt) {
        const bf16x8 pa = *(const bf16x8*)&pb[w][l15 * VTP + kt * 32 + quad * 8];
        const bf16x8 vb = *(const bf16x8*)&Vt[(ntl * 16 + l15) * VTP + kt * 32 + quad * 8];
        o = __builtin_amdgcn_mfma_f32_16x16x32_bf16(pa, vb, o, 0, 0, 0);
      }
#pragma unroll
      for (int r = 0; r < 4; ++r)
        Ob[(size_t)(b * NSEQ + q0 + quad * 4 + r) * NC + h * NDH + ntl * 16 + l15] =
            f2bf(o[r]);
    }
    a0 = n0;
    a1 = n1;
  }
}

extern "C" void kernel_launch(void* const* d_in, const int* in_sizes, int n_in,
                              void* d_out, int out_size, void* d_ws, size_t ws_size,
                              hipStream_t stream) {
  const float* x = (const float*)d_in[0];
  const float* cond = (const float*)d_in[1];
  const int* mask = (const int*)d_in[2];
  const float* Wq = (const float*)d_in[3];
  const float* bq = (const float*)d_in[4];
  const float* Wkv = (const float*)d_in[5];
  const float* bkv = (const float*)d_in[6];
  const float* Wp = (const float*)d_in[7];
  const float* bp = (const float*)d_in[8];

  char* ws = (char*)d_ws;
  u16* xb = (u16*)(ws + 0);
  u16* condb = (u16*)(ws + 33554432);
  u16* Wqb = (u16*)(ws + 37486592);
  u16* Wkvb = (u16*)(ws + 39583744);
  u16* Wpb = (u16*)(ws + 43778048);
  u16* Qb = (u16*)(ws + 45875200);
  u16* KVb = (u16*)(ws + 79429632);
  u16* Ob = xb;

  cast_all<<<22400, 256, 0, stream>>>(x, xb, cond, condb, Wq, Wqb, Wkv, Wkvb, Wp, Wpb);

  gemm256<false><<<256, 512, 0, stream>>>(xb, Wqb, bq, Qb, 16384, 1024, 1024);
  gemm_bt<false><<<15 * 16, 256, 0, stream>>>(condb, Wkvb, bkv, KVb, 1920, 2048, 1024);
  attn<<<1024, 256, 0, stream>>>(Qb, KVb, mask, Ob);
  gemm256<true><<<256, 512, 0, stream>>>(Ob, Wpb, bp, d_out, 16384, 1024, 1024);
}

// Round 3
// 276.860 us; speedup vs baseline: 1.1917x; 1.0065x over previous
//
#include <hip/hip_runtime.h>

typedef unsigned short u16;
typedef unsigned int u32;
typedef float f32x4 __attribute__((ext_vector_type(4)));
typedef __bf16 bf16x8 __attribute__((ext_vector_type(8)));
typedef u32 u32x4 __attribute__((ext_vector_type(4)));
typedef u16 u16x4 __attribute__((ext_vector_type(4)));

#define NB 16
#define NSEQ 1024
#define NL 120
#define NLP 128
#define NC 1024
#define NH 16
#define NDH 64
#define KSP 72
#define VTP 136

__device__ __forceinline__ u16 f2bf(float f) {
  u32 u = __float_as_uint(f);
  return (u16)((u + 0x7fffu + ((u >> 16) & 1u)) >> 16);  // RNE
}

__device__ __forceinline__ void gld_lds16(const void* g, void* l) {
  __builtin_amdgcn_global_load_lds(
      (const __attribute__((address_space(1))) void*)g,
      (__attribute__((address_space(3))) void*)l, 16, 0, 0);
}

#define SBAR()                               \
  do {                                       \
    __builtin_amdgcn_sched_barrier(0);       \
    __builtin_amdgcn_s_barrier();            \
    __builtin_amdgcn_sched_barrier(0);       \
  } while (0)
#define VMW(n)                                          \
  do {                                                  \
    __builtin_amdgcn_sched_barrier(0);                  \
    asm volatile("s_waitcnt vmcnt(" #n ")" ::: "memory"); \
  } while (0)
#define SB0() __builtin_amdgcn_sched_barrier(0)

// one launch casts all five fp32 tensors to bf16; segment bounds compile-time
__global__ __launch_bounds__(256) void cast_all(
    const float* __restrict__ x, u16* __restrict__ xb,
    const float* __restrict__ cond, u16* __restrict__ condb,
    const float* __restrict__ Wq, u16* __restrict__ Wqb,
    const float* __restrict__ Wkv, u16* __restrict__ Wkvb,
    const float* __restrict__ Wp, u16* __restrict__ Wpb) {
  int bk = blockIdx.x;
  const float* src;
  u16* dst;
  if (bk < 16384) { src = x; dst = xb; }
  else if (bk < 18304) { src = cond; dst = condb; bk -= 16384; }
  else if (bk < 19328) { src = Wq; dst = Wqb; bk -= 18304; }
  else if (bk < 21376) { src = Wkv; dst = Wkvb; bk -= 19328; }
  else { src = Wp; dst = Wpb; bk -= 21376; }
  size_t i = ((size_t)bk * 256 + threadIdx.x) * 4;
  f32x4 v = *(const f32x4*)(src + i);
  u16x4 o;
  o.x = f2bf(v.x); o.y = f2bf(v.y); o.z = f2bf(v.z); o.w = f2bf(v.w);
  *(u16x4*)(dst + i) = o;
}

// ---------------------------------------------------------------------------
// 128x128 m97-structure GEMM: kept for the KV projection (M=1920 not /256).
// ---------------------------------------------------------------------------
template <bool OUT_F32>
__global__ __launch_bounds__(256) void gemm_bt(
    const u16* __restrict__ A, const u16* __restrict__ Bt,
    const float* __restrict__ bias, void* __restrict__ Cout,
    int M, int Nn, int K) {
  __shared__ u16 As[128 * 32];
  __shared__ u16 Bs[128 * 32];
  const int mt = M >> 7;
  const int bm = (int)blockIdx.x % mt;
  const int bn = (int)blockIdx.x / mt;
  const int m0 = bm << 7, n0 = bn << 7;
  const int tid = threadIdx.x;
  const int w = tid >> 6, lane = tid & 63;
  const int wm = (w & 1) << 6, wn = (w >> 1) << 6;
  const int quad = lane >> 4, l15 = lane & 15;

  f32x4 acc[4][4];
#pragma unroll
  for (int i = 0; i < 4; ++i)
#pragma unroll
    for (int j = 0; j < 4; ++j) acc[i][j] = (f32x4){0.f, 0.f, 0.f, 0.f};

  const int r0 = tid >> 2;
  const int cb = ((((tid & 3) - (r0 >> 1)) & 3)) << 3;
  const u16* aP = A + (size_t)(m0 + r0) * K + cb;
  const u16* bP = Bt + (size_t)(n0 + r0) * K + cb;
  u16* asDst = &As[r0 * 32 + ((tid & 3) << 3)];
  u16* bsDst = &Bs[r0 * 32 + ((tid & 3) << 3)];

  const int sw = ((quad + (l15 >> 1)) & 3) << 3;

  for (int k0 = 0; k0 < K; k0 += 32) {
    __syncthreads();
    gld_lds16(aP + k0, asDst);
    gld_lds16(aP + (size_t)64 * K + k0, asDst + 64 * 32);
    gld_lds16(bP + k0, bsDst);
    gld_lds16(bP + (size_t)64 * K + k0, bsDst + 64 * 32);
    __syncthreads();

    bf16x8 af[4], bfr[4];
#pragma unroll
    for (int i = 0; i < 4; ++i)
      af[i] = *(const bf16x8*)&As[(wm + i * 16 + l15) * 32 + sw];
#pragma unroll
    for (int j = 0; j < 4; ++j)
      bfr[j] = *(const bf16x8*)&Bs[(wn + j * 16 + l15) * 32 + sw];
#pragma unroll
    for (int i = 0; i < 4; ++i)
#pragma unroll
      for (int j = 0; j < 4; ++j)
        acc[i][j] =
            __builtin_amdgcn_mfma_f32_16x16x32_bf16(af[i], bfr[j], acc[i][j], 0, 0, 0);
  }

#pragma unroll
  for (int j = 0; j < 4; ++j) {
    const int col = n0 + wn + j * 16 + l15;
    const float bv = bias[col];
#pragma unroll
    for (int i = 0; i < 4; ++i) {
      const int row = m0 + wm + i * 16 + quad * 4;
#pragma unroll
      for (int r = 0; r < 4; ++r) {
        const float v = acc[i][j][r] + bv;
        if (OUT_F32)
          ((float*)Cout)[(size_t)(row + r) * Nn + col] = v;
        else
          ((u16*)Cout)[(size_t)(row + r) * Nn + col] = f2bf(v);
      }
    }
  }
}

// ---------------------------------------------------------------------------
// 256x256-tile, BK=64, 8-wave, 8-phase pipelined GEMM.
// R3 changes vs R2:
//  * Fragment PREFETCH one phase ahead (double-banked af/bl/bh registers):
//    phase p issues ds_reads for p+1 just before MM(p), so the LDS pipe
//    drains while the matrix pipe runs. R2 read-then-MFMA serialized the
//    two pipes (~3000cy LDS + ~4950cy MFMA + barriers = 13.6k cyc/iter
//    observed vs m201's 6.6k).
//  * ONE barrier per phase (VMW moved before SBAR so the all-waves-staged
//    guarantee still holds at the barrier): 8 barriers/iter, was 16.
//    pf availability re-traced: ph2's VMW completes T(2it).Ahi+T(2it+1).Alo,
//    ph4: T(2it+1).Bhi+Blo, ph6: T(2it+1).Ahi+T(2it+2).Alo, ph8:
//    T(2it+2).Bhi+Blo -> every pf is after the wait that completes its data,
//    and every concurrent {pf(p) read, STAGE(p+1) write} pair is region-
//    disjoint (max wave skew = 1 phase via the barrier).
//  * XCD remap: each XCD owns a contiguous 8-wide bm chunk across ALL bn,
//    so the 4 bn-blocks sharing an A-panel sit on ONE XCD -> A fetched from
//    HBM once (R2 FETCH 67.6MB ~= 2x A). B (2MB) stays L2-resident.
// ---------------------------------------------------------------------------
template <bool OUT_F32>
__global__ __launch_bounds__(512, 2) void gemm256(
    const u16* __restrict__ A, const u16* __restrict__ Bt,
    const float* __restrict__ bias, void* __restrict__ Cout,
    int M, int Nn, int K) {
  __shared__ u16 S[2][2][2][8192];  // [A/B][buf][half][128*64]

  const int bid = (int)blockIdx.x;
  const int mt = M >> 8;
  const int mpx = mt >> 3;  // bm chunk per XCD (mt assumed %8==0)
  const int xcd = bid & 7, idx = bid >> 3;
  const int bm = xcd * mpx + (idx % mpx);
  const int bn = idx / mpx;
  const int m0 = bm << 8, n0 = bn << 8;

  const int tid = threadIdx.x;
  const int w = tid >> 6, lane = tid & 63;
  const int quad = lane >> 4, l15 = lane & 15;
  const int wr = w & 1, wc = w >> 1;

  const int srow = tid >> 3;
  const int xoff = (((tid & 7) ^ (srow & 7)) << 3);  // u16 units
  const u16* aB0 = A + (size_t)(m0 + srow) * K + xoff;
  const u16* bB0 = Bt + (size_t)(n0 + srow) * K + xoff;
  const size_t rowK64 = (size_t)64 * K;
  const size_t rowK128 = (size_t)128 * K;

  auto STAGE = [&](int ab, int buf, int half, int t) {
    const u16* g = (ab ? bB0 : aB0) + half * rowK128 + t * 64;
    u16* d = &S[ab][buf][half][0] + tid * 8;
    gld_lds16(g, d);
    gld_lds16(g + rowK64, d + 4096);
  };

  const int c0 = ((quad << 4) ^ ((l15 & 7) << 4));
  const int c1 = c0 ^ 64;
  const int arow = (wr * 64 + l15) * 128;  // bytes within A half
  const int brow = (wc * 32 + l15) * 128;  // bytes within B half

  // double-banked fragment registers (pf one phase ahead)
  bf16x8 afA[4][2], afB[4][2], blA[2][2], blB[2][2], bhA[2][2], bhB[2][2];
  auto LDA_TO = [&](bf16x8(&dst)[4][2], int buf, int rh) {
    const char* base = (const char*)&S[0][buf][rh][0] + arow;
#pragma unroll
    for (int f = 0; f < 4; ++f) {
      dst[f][0] = *(const bf16x8*)(base + f * 2048 + c0);
      dst[f][1] = *(const bf16x8*)(base + f * 2048 + c1);
    }
  };
  auto LDB_TO = [&](bf16x8(&dst)[2][2], int buf, int ch) {
    const char* base = (const char*)&S[1][buf][ch][0] + brow;
#pragma unroll
    for (int g = 0; g < 2; ++g) {
      dst[g][0] = *(const bf16x8*)(base + g * 2048 + c0);
      dst[g][1] = *(const bf16x8*)(base + g * 2048 + c1);
    }
  };

  f32x4 a_ll[4][2], a_lh[4][2], a_hh[4][2], a_hl[4][2];
#pragma unroll
  for (int f = 0; f < 4; ++f)
#pragma unroll
    for (int g = 0; g < 2; ++g) {
      a_ll[f][g] = (f32x4){0.f, 0.f, 0.f, 0.f};
      a_lh[f][g] = (f32x4){0.f, 0.f, 0.f, 0.f};
      a_hh[f][g] = (f32x4){0.f, 0.f, 0.f, 0.f};
      a_hl[f][g] = (f32x4){0.f, 0.f, 0.f, 0.f};
    }

  auto MM = [&](f32x4(&acc)[4][2], bf16x8(&af)[4][2], bf16x8(&bf)[2][2]) {
    __builtin_amdgcn_s_setprio(1);
#pragma unroll
    for (int f = 0; f < 4; ++f)
#pragma unroll
      for (int g = 0; g < 2; ++g) {
        acc[f][g] = __builtin_amdgcn_mfma_f32_16x16x32_bf16(af[f][0], bf[g][0],
                                                            acc[f][g], 0, 0, 0);
        acc[f][g] = __builtin_amdgcn_mfma_f32_16x16x32_bf16(af[f][1], bf[g][1],
                                                            acc[f][g], 0, 0, 0);
      }
    __builtin_amdgcn_s_setprio(0);
  };

  const int NT = K >> 6;
  const int NIT = K >> 7;

  // prologue: T0 fully + T1.{Alo,Bhi}; T1's 4 loads stay in flight.
  STAGE(0, 0, 0, 0); STAGE(0, 0, 1, 0); STAGE(1, 0, 0, 0); STAGE(1, 0, 1, 0);
  STAGE(0, 1, 0, 1); STAGE(1, 1, 1, 1);
  VMW(4);
  SBAR();
  LDA_TO(afA, 0, 0); LDB_TO(blA, 0, 0);  // pf for ph1
  SB0();

#pragma unroll 1
  for (int it = 0; it < NIT; ++it) {
    const int t1 = 2 * it + 1;
    int t2 = 2 * it + 2; if (t2 > NT - 1) t2 = NT - 1;
    int t3 = 2 * it + 3; if (t3 > NT - 1) t3 = NT - 1;
    // ph1
    STAGE(1, 1, 0, t1);
    SBAR();
    LDB_TO(bhA, 0, 1); SB0();
    MM(a_ll, afA, blA);
    // ph2
    STAGE(0, 1, 1, t1); VMW(6);
    SBAR();
    LDA_TO(afB, 0, 1); SB0();
    MM(a_lh, afA, bhA);
    // ph3
    STAGE(0, 0, 0, t2);
    SBAR();
    MM(a_hh, afB, bhA);
    // ph4
    STAGE(1, 0, 1, t2); VMW(6);
    SBAR();
    LDA_TO(afA, 1, 0); LDB_TO(blB, 1, 0); SB0();
    MM(a_hl, afB, blA);
    // ph5
    STAGE(1, 0, 0, t2);
    SBAR();
    LDB_TO(bhB, 1, 1); SB0();
    MM(a_ll, afA, blB);
    // ph6
    STAGE(0, 0, 1, t2); VMW(6);
    SBAR();
    LDA_TO(afB, 1, 1); SB0();
    MM(a_lh, afA, bhB);
    // ph7
    STAGE(0, 1, 0, t3);
    SBAR();
    MM(a_hh, afB, bhB);
    // ph8
    STAGE(1, 1, 1, t3); VMW(6);
    SBAR();
    LDA_TO(afA, 0, 0); LDB_TO(blA, 0, 0); SB0();
    MM(a_hl, afB, blB);
  }

  // epilogue: C/D layout col=lane&15, row=quad*4+reg  [verified m89/m91]
  auto EPI = [&](f32x4(&acc)[4][2], int rh, int ch) {
#pragma unroll
    for (int g = 0; g < 2; ++g) {
      const int col = n0 + ch * 128 + wc * 32 + g * 16 + l15;
      const float bv = bias[col];
#pragma unroll
      for (int f = 0; f < 4; ++f) {
        const int row = m0 + rh * 128 + wr * 64 + f * 16 + quad * 4;
#pragma unroll
        for (int r = 0; r < 4; ++r) {
          const float v = acc[f][g][r] + bv;
          if (OUT_F32)
            ((float*)Cout)[(size_t)(row + r) * Nn + col] = v;
          else
            ((u16*)Cout)[(size_t)(row + r) * Nn + col] = f2bf(v);
        }
      }
    }
  };
  EPI(a_ll, 0, 0); EPI(a_lh, 0, 1); EPI(a_hh, 1, 1); EPI(a_hl, 1, 0);
}

// one block per (b,h,chunk-of-256-queries); K/V/mask staged in LDS once;
// 4 waves x 16 queries/iter x 4 iters. (unchanged from R2)
__global__ __launch_bounds__(256) void attn(
    const u16* __restrict__ Qb, const u16* __restrict__ KVb,
    const int* __restrict__ mask, u16* __restrict__ Ob) {
  __shared__ u16 Ks[NLP * KSP];
  __shared__ u16 Vt[NDH * VTP];
  __shared__ float mb[NLP];
  __shared__ u16 pb[4][16 * VTP];

  const int chunk = (int)blockIdx.x & 3;
  const int h = ((int)blockIdx.x >> 2) & 15;
  const int b = (int)blockIdx.x >> 6;
  const int tid = threadIdx.x;
  const int w = tid >> 6, lane = tid & 63;
  const int quad = lane >> 4, l15 = lane & 15;
  const u16* kvbase = KVb + (size_t)b * NL * 2 * NC;

  for (int i = tid; i < NLP * 8; i += 256) {
    const int l = i >> 3, c8 = (i & 7) * 8;
    u32x4 z = {0u, 0u, 0u, 0u};
    u32x4 v = (l < NL) ? *(const u32x4*)(kvbase + (size_t)l * 2 * NC + h * NDH + c8) : z;
    *(u32x4*)&Ks[l * KSP + c8] = v;
  }
  u16* vstage = &pb[0][0];
  for (int i = tid; i < NL * 8; i += 256) {
    const int l = i >> 3, c8 = (i & 7) * 8;
    *(u32x4*)&vstage[l * NDH + c8] =
        *(const u32x4*)(kvbase + (size_t)l * 2 * NC + NC + h * NDH + c8);
  }
  for (int i = tid; i < NLP; i += 256)
    mb[i] = (i < NL && mask[b * NL + i] != 0) ? 0.0f : -1e30f;
  __syncthreads();
  {
    const int d = tid & 63;
#pragma unroll
    for (int it2 = 0; it2 < 8; ++it2) {
      const int l4 = (tid >> 6) + it2 * 4;  // 0..31
      u16x4 vv;
      if (l4 < 30) {
        vv.x = vstage[(l4 * 4 + 0) * NDH + d];
        vv.y = vstage[(l4 * 4 + 1) * NDH + d];
        vv.z = vstage[(l4 * 4 + 2) * NDH + d];
        vv.w = vstage[(l4 * 4 + 3) * NDH + d];
      } else {
        vv = (u16x4){0, 0, 0, 0};
      }
      *(u16x4*)&Vt[d * VTP + l4 * 4] = vv;
    }
  }
  __syncthreads();

  const float scale = 0.125f;
  const u16* qbase = Qb + (size_t)(b * NSEQ + chunk * 256 + l15) * NC + h * NDH + quad * 8;
  bf16x8 a0 = *(const bf16x8*)(qbase + (size_t)(0 * 64 + w * 16) * NC);
  bf16x8 a1 = *(const bf16x8*)(qbase + (size_t)(0 * 64 + w * 16) * NC + 32);

  for (int it = 0; it < 4; ++it) {
    const int q0 = chunk * 256 + it * 64 + w * 16;
    const int itn = (it + 1) & 3;
    const u16* qn = qbase + (size_t)(itn * 64 + w * 16) * NC;
    const bf16x8 n0 = *(const bf16x8*)qn;
    const bf16x8 n1 = *(const bf16x8*)(qn + 32);

    f32x4 s[8];
#pragma unroll
    for (int kt = 0; kt < 8; ++kt) {
      const u16* kb = &Ks[(kt * 16 + l15) * KSP + quad * 8];
      const bf16x8 b0 = *(const bf16x8*)kb;
      const bf16x8 b1 = *(const bf16x8*)(kb + 32);
      f32x4 t = {0.f, 0.f, 0.f, 0.f};
      t = __builtin_amdgcn_mfma_f32_16x16x32_bf16(a0, b0, t, 0, 0, 0);
      t = __builtin_amdgcn_mfma_f32_16x16x32_bf16(a1, b1, t, 0, 0, 0);
      s[kt] = t;
    }
#pragma unroll
    for (int kt = 0; kt < 8; ++kt) {
      const float mbv = mb[kt * 16 + l15];
#pragma unroll
      for (int r = 0; r < 4; ++r) s[kt][r] = s[kt][r] * scale + mbv;
    }
    float sum[4];
#pragma unroll
    for (int r = 0; r < 4; ++r) {
      float m = s[0][r];
#pragma unroll
      for (int kt = 1; kt < 8; ++kt) m = fmaxf(m, s[kt][r]);
      m = fmaxf(m, __shfl_xor(m, 1));
      m = fmaxf(m, __shfl_xor(m, 2));
      m = fmaxf(m, __shfl_xor(m, 4));
      m = fmaxf(m, __shfl_xor(m, 8));
      float su = 0.f;
#pragma unroll
      for (int kt = 0; kt < 8; ++kt) {
        s[kt][r] = __expf(s[kt][r] - m);
        su += s[kt][r];
      }
      su += __shfl_xor(su, 1);
      su += __shfl_xor(su, 2);
      su += __shfl_xor(su, 4);
      su += __shfl_xor(su, 8);
      sum[r] = su;
    }
#pragma unroll
    for (int r = 0; r < 4; ++r) {
      const float inv = 1.0f / sum[r];
#pragma unroll
      for (int kt = 0; kt < 8; ++kt)
        pb[w][(quad * 4 + r) * VTP + kt * 16 + l15] = f2bf(s[kt][r] * inv);
    }
#pragma unroll
    for (int ntl = 0; ntl < 4; ++ntl) {
      f32x4 o = {0.f, 0.f, 0.f, 0.f};
#pragma unroll
      for (int kt = 0; kt < 4; ++kt) {
        const bf16x8 pa = *(const bf16x8*)&pb[w][l15 * VTP + kt * 32 + quad * 8];
        const bf16x8 vb = *(const bf16x8*)&Vt[(ntl * 16 + l15) * VTP + kt * 32 + quad * 8];
        o = __builtin_amdgcn_mfma_f32_16x16x32_bf16(pa, vb, o, 0, 0, 0);
      }
#pragma unroll
      for (int r = 0; r < 4; ++r)
        Ob[(size_t)(b * NSEQ + q0 + quad * 4 + r) * NC + h * NDH + ntl * 16 + l15] =
            f2bf(o[r]);
    }
    a0 = n0;
    a1 = n1;
  }
}

extern "C" void kernel_launch(void* const* d_in, const int* in_sizes, int n_in,
                              void* d_out, int out_size, void* d_ws, size_t ws_size,
                              hipStream_t stream) {
  const float* x = (const float*)d_in[0];
  const float* cond = (const float*)d_in[1];
  const int* mask = (const int*)d_in[2];
  const float* Wq = (const float*)d_in[3];
  const float* bq = (const float*)d_in[4];
  const float* Wkv = (const float*)d_in[5];
  const float* bkv = (const float*)d_in[6];
  const float* Wp = (const float*)d_in[7];
  const float* bp = (const float*)d_in[8];

  char* ws = (char*)d_ws;
  u16* xb = (u16*)(ws + 0);
  u16* condb = (u16*)(ws + 33554432);
  u16* Wqb = (u16*)(ws + 37486592);
  u16* Wkvb = (u16*)(ws + 39583744);
  u16* Wpb = (u16*)(ws + 43778048);
  u16* Qb = (u16*)(ws + 45875200);
  u16* KVb = (u16*)(ws + 79429632);
  u16* Ob = xb;

  cast_all<<<22400, 256, 0, stream>>>(x, xb, cond, condb, Wq, Wqb, Wkv, Wkvb, Wp, Wpb);

  gemm256<false><<<256, 512, 0, stream>>>(xb, Wqb, bq, Qb, 16384, 1024, 1024);
  gemm_bt<false><<<15 * 16, 256, 0, stream>>>(condb, Wkvb, bkv, KVb, 1920, 2048, 1024);
  attn<<<1024, 256, 0, stream>>>(Qb, KVb, mask, Ob);
  gemm256<true><<<256, 512, 0, stream>>>(Ob, Wpb, bp, d_out, 16384, 1024, 1024);
}

// Round 4
// 275.438 us; speedup vs baseline: 1.1978x; 1.0052x over previous
//
#include <hip/hip_runtime.h>

typedef unsigned short u16;
typedef unsigned int u32;
typedef float f32x4 __attribute__((ext_vector_type(4)));
typedef __bf16 bf16x8 __attribute__((ext_vector_type(8)));
typedef u32 u32x4 __attribute__((ext_vector_type(4)));
typedef u32 u32x2 __attribute__((ext_vector_type(2)));
typedef u16 u16x4 __attribute__((ext_vector_type(4)));

#define NB 16
#define NSEQ 1024
#define NL 120
#define NLP 128
#define NC 1024
#define NH 16
#define NDH 64
#define KSP 72
#define VTP 136

__device__ __forceinline__ u16 f2bf(float f) {
  u32 u = __float_as_uint(f);
  return (u16)((u + 0x7fffu + ((u >> 16) & 1u)) >> 16);  // RNE
}

__device__ __forceinline__ void gld_lds16(const void* g, void* l) {
  __builtin_amdgcn_global_load_lds(
      (const __attribute__((address_space(1))) void*)g,
      (__attribute__((address_space(3))) void*)l, 16, 0, 0);
}

#define SBAR()                               \
  do {                                       \
    __builtin_amdgcn_sched_barrier(0);       \
    __builtin_amdgcn_s_barrier();            \
    __builtin_amdgcn_sched_barrier(0);       \
  } while (0)
#define VMW(n)                                          \
  do {                                                  \
    __builtin_amdgcn_sched_barrier(0);                  \
    asm volatile("s_waitcnt vmcnt(" #n ")" ::: "memory"); \
  } while (0)
#define SB0() __builtin_amdgcn_sched_barrier(0)

// one launch casts all five fp32 tensors to bf16; segment bounds compile-time
__global__ __launch_bounds__(256) void cast_all(
    const float* __restrict__ x, u16* __restrict__ xb,
    const float* __restrict__ cond, u16* __restrict__ condb,
    const float* __restrict__ Wq, u16* __restrict__ Wqb,
    const float* __restrict__ Wkv, u16* __restrict__ Wkvb,
    const float* __restrict__ Wp, u16* __restrict__ Wpb) {
  int bk = blockIdx.x;
  const float* src;
  u16* dst;
  if (bk < 16384) { src = x; dst = xb; }
  else if (bk < 18304) { src = cond; dst = condb; bk -= 16384; }
  else if (bk < 19328) { src = Wq; dst = Wqb; bk -= 18304; }
  else if (bk < 21376) { src = Wkv; dst = Wkvb; bk -= 19328; }
  else { src = Wp; dst = Wpb; bk -= 21376; }
  size_t i = ((size_t)bk * 256 + threadIdx.x) * 4;
  f32x4 v = *(const f32x4*)(src + i);
  u16x4 o;
  o.x = f2bf(v.x); o.y = f2bf(v.y); o.z = f2bf(v.z); o.w = f2bf(v.w);
  *(u16x4*)(dst + i) = o;
}

// ---------------------------------------------------------------------------
// 128x128 m97-structure GEMM: kept for the KV projection (M=1920 not /256).
// ---------------------------------------------------------------------------
template <bool OUT_F32>
__global__ __launch_bounds__(256) void gemm_bt(
    const u16* __restrict__ A, const u16* __restrict__ Bt,
    const float* __restrict__ bias, void* __restrict__ Cout,
    int M, int Nn, int K) {
  __shared__ u16 As[128 * 32];
  __shared__ u16 Bs[128 * 32];
  const int mt = M >> 7;
  const int bm = (int)blockIdx.x % mt;
  const int bn = (int)blockIdx.x / mt;
  const int m0 = bm << 7, n0 = bn << 7;
  const int tid = threadIdx.x;
  const int w = tid >> 6, lane = tid & 63;
  const int wm = (w & 1) << 6, wn = (w >> 1) << 6;
  const int quad = lane >> 4, l15 = lane & 15;

  f32x4 acc[4][4];
#pragma unroll
  for (int i = 0; i < 4; ++i)
#pragma unroll
    for (int j = 0; j < 4; ++j) acc[i][j] = (f32x4){0.f, 0.f, 0.f, 0.f};

  const int r0 = tid >> 2;
  const int cb = ((((tid & 3) - (r0 >> 1)) & 3)) << 3;
  const u16* aP = A + (size_t)(m0 + r0) * K + cb;
  const u16* bP = Bt + (size_t)(n0 + r0) * K + cb;
  u16* asDst = &As[r0 * 32 + ((tid & 3) << 3)];
  u16* bsDst = &Bs[r0 * 32 + ((tid & 3) << 3)];

  const int sw = ((quad + (l15 >> 1)) & 3) << 3;

  for (int k0 = 0; k0 < K; k0 += 32) {
    __syncthreads();
    gld_lds16(aP + k0, asDst);
    gld_lds16(aP + (size_t)64 * K + k0, asDst + 64 * 32);
    gld_lds16(bP + k0, bsDst);
    gld_lds16(bP + (size_t)64 * K + k0, bsDst + 64 * 32);
    __syncthreads();

    bf16x8 af[4], bfr[4];
#pragma unroll
    for (int i = 0; i < 4; ++i)
      af[i] = *(const bf16x8*)&As[(wm + i * 16 + l15) * 32 + sw];
#pragma unroll
    for (int j = 0; j < 4; ++j)
      bfr[j] = *(const bf16x8*)&Bs[(wn + j * 16 + l15) * 32 + sw];
#pragma unroll
    for (int i = 0; i < 4; ++i)
#pragma unroll
      for (int j = 0; j < 4; ++j)
        acc[i][j] =
            __builtin_amdgcn_mfma_f32_16x16x32_bf16(af[i], bfr[j], acc[i][j], 0, 0, 0);
  }

#pragma unroll
  for (int j = 0; j < 4; ++j) {
    const int col = n0 + wn + j * 16 + l15;
    const float bv = bias[col];
#pragma unroll
    for (int i = 0; i < 4; ++i) {
      const int row = m0 + wm + i * 16 + quad * 4;
#pragma unroll
      for (int r = 0; r < 4; ++r) {
        const float v = acc[i][j][r] + bv;
        if (OUT_F32)
          ((float*)Cout)[(size_t)(row + r) * Nn + col] = v;
        else
          ((u16*)Cout)[(size_t)(row + r) * Nn + col] = f2bf(v);
      }
    }
  }
}

// ---------------------------------------------------------------------------
// 256x256-tile, BK=64, 8-wave, 8-phase pipelined GEMM.
// R4 changes vs R3:
//  * SWAPPED MFMA operands: acc = mfma(bf, af, acc) computes the C^T
//    fragment, so each lane holds 4 CONSECUTIVE columns (quad*4+r). This
//    turns the epilogue from 2B-per-lane scatter (32B runs -> 2.13x HBM
//    write amplification, WRITE 71.6MB vs 33.5 ideal, ~26k-cyc tail) into
//    packed stores.
//  * bf16 epilogue: restage C into the drained 128KB S buffer (XOR-swizzled
//    8B ds_writes, ~2-way), then fully-coalesced 16B/lane global stores
//    (512B runs). f32 epilogue: direct f32x4 (16B/lane, 64B runs).
//  * Balanced ds_read phases (<=8/phase): LDA moved ph4->ph3, ph8->ph7.
//    Data availability re-traced vs in-order vmcnt completion (it=0 and
//    steady state); all LDS WAR gaps >=3 phases.
// ---------------------------------------------------------------------------
template <bool OUT_F32>
__global__ __launch_bounds__(512, 2) void gemm256(
    const u16* __restrict__ A, const u16* __restrict__ Bt,
    const float* __restrict__ bias, void* __restrict__ Cout,
    int M, int Nn, int K) {
  __shared__ u16 S[2][2][2][8192];  // [A/B][buf][half][128*64]

  const int bid = (int)blockIdx.x;
  const int mt = M >> 8;
  const int mpx = mt >> 3;  // bm chunk per XCD (mt %8==0)
  const int xcd = bid & 7, idx = bid >> 3;
  const int bm = xcd * mpx + (idx % mpx);
  const int bn = idx / mpx;
  const int m0 = bm << 8, n0 = bn << 8;

  const int tid = threadIdx.x;
  const int w = tid >> 6, lane = tid & 63;
  const int quad = lane >> 4, l15 = lane & 15;
  const int wr = w & 1, wc = w >> 1;

  const int srow = tid >> 3;
  const int xoff = (((tid & 7) ^ (srow & 7)) << 3);  // u16 units
  const u16* aB0 = A + (size_t)(m0 + srow) * K + xoff;
  const u16* bB0 = Bt + (size_t)(n0 + srow) * K + xoff;
  const size_t rowK64 = (size_t)64 * K;
  const size_t rowK128 = (size_t)128 * K;

  auto STAGE = [&](int ab, int buf, int half, int t) {
    const u16* g = (ab ? bB0 : aB0) + half * rowK128 + t * 64;
    u16* d = &S[ab][buf][half][0] + tid * 8;
    gld_lds16(g, d);
    gld_lds16(g + rowK64, d + 4096);
  };

  const int c0 = ((quad << 4) ^ ((l15 & 7) << 4));
  const int c1 = c0 ^ 64;
  const int arow = (wr * 64 + l15) * 128;  // bytes within A half
  const int brow = (wc * 32 + l15) * 128;  // bytes within B half

  // double-banked fragment registers (pf one phase ahead)
  bf16x8 afA[4][2], afB[4][2], blA[2][2], blB[2][2], bhA[2][2], bhB[2][2];
  auto LDA_TO = [&](bf16x8(&dst)[4][2], int buf, int rh) {
    const char* base = (const char*)&S[0][buf][rh][0] + arow;
#pragma unroll
    for (int f = 0; f < 4; ++f) {
      dst[f][0] = *(const bf16x8*)(base + f * 2048 + c0);
      dst[f][1] = *(const bf16x8*)(base + f * 2048 + c1);
    }
  };
  auto LDB_TO = [&](bf16x8(&dst)[2][2], int buf, int ch) {
    const char* base = (const char*)&S[1][buf][ch][0] + brow;
#pragma unroll
    for (int g = 0; g < 2; ++g) {
      dst[g][0] = *(const bf16x8*)(base + g * 2048 + c0);
      dst[g][1] = *(const bf16x8*)(base + g * 2048 + c1);
    }
  };

  f32x4 a_ll[4][2], a_lh[4][2], a_hh[4][2], a_hl[4][2];
#pragma unroll
  for (int f = 0; f < 4; ++f)
#pragma unroll
    for (int g = 0; g < 2; ++g) {
      a_ll[f][g] = (f32x4){0.f, 0.f, 0.f, 0.f};
      a_lh[f][g] = (f32x4){0.f, 0.f, 0.f, 0.f};
      a_hh[f][g] = (f32x4){0.f, 0.f, 0.f, 0.f};
      a_hl[f][g] = (f32x4){0.f, 0.f, 0.f, 0.f};
    }

  // SWAPPED: D = mfma(B, A) -> lane l15 = C-row, quad*4+reg = C-col.
  auto MM = [&](f32x4(&acc)[4][2], bf16x8(&af)[4][2], bf16x8(&bf)[2][2]) {
    __builtin_amdgcn_s_setprio(1);
#pragma unroll
    for (int f = 0; f < 4; ++f)
#pragma unroll
      for (int g = 0; g < 2; ++g) {
        acc[f][g] = __builtin_amdgcn_mfma_f32_16x16x32_bf16(bf[g][0], af[f][0],
                                                            acc[f][g], 0, 0, 0);
        acc[f][g] = __builtin_amdgcn_mfma_f32_16x16x32_bf16(bf[g][1], af[f][1],
                                                            acc[f][g], 0, 0, 0);
      }
    __builtin_amdgcn_s_setprio(0);
  };

  const int NT = K >> 6;
  const int NIT = K >> 7;

  // prologue: T0 fully + T1.{Alo,Bhi}; T1's 4 loads stay in flight.
  STAGE(0, 0, 0, 0); STAGE(0, 0, 1, 0); STAGE(1, 0, 0, 0); STAGE(1, 0, 1, 0);
  STAGE(0, 1, 0, 1); STAGE(1, 1, 1, 1);
  VMW(4);
  SBAR();
  LDA_TO(afA, 0, 0); LDB_TO(blA, 0, 0);  // pf for ph1
  SB0();

#pragma unroll 1
  for (int it = 0; it < NIT; ++it) {
    const int t1 = 2 * it + 1;
    int t2 = 2 * it + 2; if (t2 > NT - 1) t2 = NT - 1;
    int t3 = 2 * it + 3; if (t3 > NT - 1) t3 = NT - 1;
    // ph1
    STAGE(1, 1, 0, t1);
    SBAR();
    LDB_TO(bhA, 0, 1); SB0();
    MM(a_ll, afA, blA);
    // ph2
    STAGE(0, 1, 1, t1); VMW(6);
    SBAR();
    LDA_TO(afB, 0, 1); SB0();
    MM(a_lh, afA, bhA);
    // ph3
    STAGE(0, 0, 0, t2);
    SBAR();
    LDA_TO(afA, 1, 0); SB0();
    MM(a_hh, afB, bhA);
    // ph4
    STAGE(1, 0, 1, t2); VMW(6);
    SBAR();
    LDB_TO(blB, 1, 0); SB0();
    MM(a_hl, afB, blA);
    // ph5
    STAGE(1, 0, 0, t2);
    SBAR();
    LDB_TO(bhB, 1, 1); SB0();
    MM(a_ll, afA, blB);
    // ph6
    STAGE(0, 0, 1, t2); VMW(6);
    SBAR();
    LDA_TO(afB, 1, 1); SB0();
    MM(a_lh, afA, bhB);
    // ph7
    STAGE(0, 1, 0, t3);
    SBAR();
    LDA_TO(afA, 0, 0); SB0();
    MM(a_hh, afB, bhB);
    // ph8
    STAGE(1, 1, 1, t3); VMW(6);
    SBAR();
    LDB_TO(blA, 0, 0); SB0();
    MM(a_hl, afB, blB);
  }

  // epilogue. Swapped-acc layout:
  //   acc[f][g][r] = C[rh*128+wr*64+f*16+l15][ch*128+wc*32+g*16+quad*4+r]
  f32x4 bv[2][2];
#pragma unroll
  for (int ch = 0; ch < 2; ++ch)
#pragma unroll
    for (int g = 0; g < 2; ++g)
      bv[ch][g] = *(const f32x4*)&bias[n0 + ch * 128 + wc * 32 + g * 16 + quad * 4];

  if (OUT_F32) {
    auto EPI32 = [&](f32x4(&acc)[4][2], int rh, int ch) {
#pragma unroll
      for (int f = 0; f < 4; ++f) {
        const int row = m0 + rh * 128 + wr * 64 + f * 16 + l15;
#pragma unroll
        for (int g = 0; g < 2; ++g) {
          const int col = n0 + ch * 128 + wc * 32 + g * 16 + quad * 4;
          f32x4 v = acc[f][g] + bv[ch][g];
          *(f32x4*)&((float*)Cout)[(size_t)row * Nn + col] = v;
        }
      }
    };
    EPI32(a_ll, 0, 0); EPI32(a_lh, 0, 1); EPI32(a_hh, 1, 1); EPI32(a_hl, 1, 0);
  } else {
    // drain in-flight gld_lds writes + own ds_reads, then reuse S as C-tile
    asm volatile("s_waitcnt vmcnt(0) lgkmcnt(0)" ::: "memory");
    __syncthreads();
    u16* Cs = &S[0][0][0][0];  // 256 x 256 u16, col XOR-swizzled by row
    auto STG = [&](f32x4(&acc)[4][2], int rh, int ch) {
#pragma unroll
      for (int f = 0; f < 4; ++f) {
        const int row = rh * 128 + wr * 64 + f * 16 + l15;
        const int sx = (row & 15) << 2;
#pragma unroll
        for (int g = 0; g < 2; ++g) {
          const int col = ch * 128 + wc * 32 + g * 16 + quad * 4;
          u16x4 o;
          o.x = f2bf(acc[f][g][0] + bv[ch][g][0]);
          o.y = f2bf(acc[f][g][1] + bv[ch][g][1]);
          o.z = f2bf(acc[f][g][2] + bv[ch][g][2]);
          o.w = f2bf(acc[f][g][3] + bv[ch][g][3]);
          *(u16x4*)&Cs[row * 256 + (col ^ sx)] = o;
        }
      }
    };
    STG(a_ll, 0, 0); STG(a_lh, 0, 1); STG(a_hh, 1, 1); STG(a_hl, 1, 0);
    __syncthreads();
    // coalesced store: per instr a wave covers 2 full rows (512B runs)
#pragma unroll
    for (int itr = 0; itr < 16; ++itr) {
      const int row = itr * 16 + w * 2 + (lane >> 5);
      const int sx = (row & 15) << 2;
      const int c = (lane & 31) * 8;
      u32x2 lo = *(const u32x2*)&Cs[row * 256 + (c ^ sx)];
      u32x2 hi = *(const u32x2*)&Cs[row * 256 + ((c + 4) ^ sx)];
      u32x4 o = {lo.x, lo.y, hi.x, hi.y};
      *(u32x4*)&((u16*)Cout)[(size_t)(m0 + row) * Nn + n0 + c] = o;
    }
  }
}

// one block per (b,h,chunk-of-256-queries); K/V/mask staged in LDS once;
// 4 waves x 16 queries/iter x 4 iters. (unchanged from R3)
__global__ __launch_bounds__(256) void attn(
    const u16* __restrict__ Qb, const u16* __restrict__ KVb,
    const int* __restrict__ mask, u16* __restrict__ Ob) {
  __shared__ u16 Ks[NLP * KSP];
  __shared__ u16 Vt[NDH * VTP];
  __shared__ float mb[NLP];
  __shared__ u16 pb[4][16 * VTP];

  const int chunk = (int)blockIdx.x & 3;
  const int h = ((int)blockIdx.x >> 2) & 15;
  const int b = (int)blockIdx.x >> 6;
  const int tid = threadIdx.x;
  const int w = tid >> 6, lane = tid & 63;
  const int quad = lane >> 4, l15 = lane & 15;
  const u16* kvbase = KVb + (size_t)b * NL * 2 * NC;

  for (int i = tid; i < NLP * 8; i += 256) {
    const int l = i >> 3, c8 = (i & 7) * 8;
    u32x4 z = {0u, 0u, 0u, 0u};
    u32x4 v = (l < NL) ? *(const u32x4*)(kvbase + (size_t)l * 2 * NC + h * NDH + c8) : z;
    *(u32x4*)&Ks[l * KSP + c8] = v;
  }
  u16* vstage = &pb[0][0];
  for (int i = tid; i < NL * 8; i += 256) {
    const int l = i >> 3, c8 = (i & 7) * 8;
    *(u32x4*)&vstage[l * NDH + c8] =
        *(const u32x4*)(kvbase + (size_t)l * 2 * NC + NC + h * NDH + c8);
  }
  for (int i = tid; i < NLP; i += 256)
    mb[i] = (i < NL && mask[b * NL + i] != 0) ? 0.0f : -1e30f;
  __syncthreads();
  {
    const int d = tid & 63;
#pragma unroll
    for (int it2 = 0; it2 < 8; ++it2) {
      const int l4 = (tid >> 6) + it2 * 4;  // 0..31
      u16x4 vv;
      if (l4 < 30) {
        vv.x = vstage[(l4 * 4 + 0) * NDH + d];
        vv.y = vstage[(l4 * 4 + 1) * NDH + d];
        vv.z = vstage[(l4 * 4 + 2) * NDH + d];
        vv.w = vstage[(l4 * 4 + 3) * NDH + d];
      } else {
        vv = (u16x4){0, 0, 0, 0};
      }
      *(u16x4*)&Vt[d * VTP + l4 * 4] = vv;
    }
  }
  __syncthreads();

  const float scale = 0.125f;
  const u16* qbase = Qb + (size_t)(b * NSEQ + chunk * 256 + l15) * NC + h * NDH + quad * 8;
  bf16x8 a0 = *(const bf16x8*)(qbase + (size_t)(0 * 64 + w * 16) * NC);
  bf16x8 a1 = *(const bf16x8*)(qbase + (size_t)(0 * 64 + w * 16) * NC + 32);

  for (int it = 0; it < 4; ++it) {
    const int q0 = chunk * 256 + it * 64 + w * 16;
    const int itn = (it + 1) & 3;
    const u16* qn = qbase + (size_t)(itn * 64 + w * 16) * NC;
    const bf16x8 n0 = *(const bf16x8*)qn;
    const bf16x8 n1 = *(const bf16x8*)(qn + 32);

    f32x4 s[8];
#pragma unroll
    for (int kt = 0; kt < 8; ++kt) {
      const u16* kb = &Ks[(kt * 16 + l15) * KSP + quad * 8];
      const bf16x8 b0 = *(const bf16x8*)kb;
      const bf16x8 b1 = *(const bf16x8*)(kb + 32);
      f32x4 t = {0.f, 0.f, 0.f, 0.f};
      t = __builtin_amdgcn_mfma_f32_16x16x32_bf16(a0, b0, t, 0, 0, 0);
      t = __builtin_amdgcn_mfma_f32_16x16x32_bf16(a1, b1, t, 0, 0, 0);
      s[kt] = t;
    }
#pragma unroll
    for (int kt = 0; kt < 8; ++kt) {
      const float mbv = mb[kt * 16 + l15];
#pragma unroll
      for (int r = 0; r < 4; ++r) s[kt][r] = s[kt][r] * scale + mbv;
    }
    float sum[4];
#pragma unroll
    for (int r = 0; r < 4; ++r) {
      float m = s[0][r];
#pragma unroll
      for (int kt = 1; kt < 8; ++kt) m = fmaxf(m, s[kt][r]);
      m = fmaxf(m, __shfl_xor(m, 1));
      m = fmaxf(m, __shfl_xor(m, 2));
      m = fmaxf(m, __shfl_xor(m, 4));
      m = fmaxf(m, __shfl_xor(m, 8));
      float su = 0.f;
#pragma unroll
      for (int kt = 0; kt < 8; ++kt) {
        s[kt][r] = __expf(s[kt][r] - m);
        su += s[kt][r];
      }
      su += __shfl_xor(su, 1);
      su += __shfl_xor(su, 2);
      su += __shfl_xor(su, 4);
      su += __shfl_xor(su, 8);
      sum[r] = su;
    }
#pragma unroll
    for (int r = 0; r < 4; ++r) {
      const float inv = 1.0f / sum[r];
#pragma unroll
      for (int kt = 0; kt < 8; ++kt)
        pb[w][(quad * 4 + r) * VTP + kt * 16 + l15] = f2bf(s[kt][r] * inv);
    }
#pragma unroll
    for (int ntl = 0; ntl < 4; ++ntl) {
      f32x4 o = {0.f, 0.f, 0.f, 0.f};
#pragma unroll
      for (int kt = 0; kt < 4; ++kt) {
        const bf16x8 pa = *(const bf16x8*)&pb[w][l15 * VTP + kt * 32 + quad * 8];
        const bf16x8 vb = *(const bf16x8*)&Vt[(ntl * 16 + l15) * VTP + kt * 32 + quad * 8];
        o = __builtin_amdgcn_mfma_f32_16x16x32_bf16(pa, vb, o, 0, 0, 0);
      }
#pragma unroll
      for (int r = 0; r < 4; ++r)
        Ob[(size_t)(b * NSEQ + q0 + quad * 4 + r) * NC + h * NDH + ntl * 16 + l15] =
            f2bf(o[r]);
    }
    a0 = n0;
    a1 = n1;
  }
}

extern "C" void kernel_launch(void* const* d_in, const int* in_sizes, int n_in,
                              void* d_out, int out_size, void* d_ws, size_t ws_size,
                              hipStream_t stream) {
  const float* x = (const float*)d_in[0];
  const float* cond = (const float*)d_in[1];
  const int* mask = (const int*)d_in[2];
  const float* Wq = (const float*)d_in[3];
  const float* bq = (const float*)d_in[4];
  const float* Wkv = (const float*)d_in[5];
  const float* bkv = (const float*)d_in[6];
  const float* Wp = (const float*)d_in[7];
  const float* bp = (const float*)d_in[8];

  char* ws = (char*)d_ws;
  u16* xb = (u16*)(ws + 0);
  u16* condb = (u16*)(ws + 33554432);
  u16* Wqb = (u16*)(ws + 37486592);
  u16* Wkvb = (u16*)(ws + 39583744);
  u16* Wpb = (u16*)(ws + 43778048);
  u16* Qb = (u16*)(ws + 45875200);
  u16* KVb = (u16*)(ws + 79429632);
  u16* Ob = xb;

  cast_all<<<22400, 256, 0, stream>>>(x, xb, cond, condb, Wq, Wqb, Wkv, Wkvb, Wp, Wpb);

  gemm256<false><<<256, 512, 0, stream>>>(xb, Wqb, bq, Qb, 16384, 1024, 1024);
  gemm_bt<false><<<15 * 16, 256, 0, stream>>>(condb, Wkvb, bkv, KVb, 1920, 2048, 1024);
  attn<<<1024, 256, 0, stream>>>(Qb, KVb, mask, Ob);
  gemm256<true><<<256, 512, 0, stream>>>(Ob, Wpb, bp, d_out, 16384, 1024, 1024);
}